// Round 3
// baseline (548.130 us; speedup 1.0000x reference)
//
#include <hip/hip_runtime.h>
#include <hip/hip_bf16.h>

#define HH 256
#define WW 832
#define OHH 128
#define OWW 208
#define NCAND 240
#define KSEL 32
#define MM (OHH*OWW)

__device__ __forceinline__ int iclamp(int v, int lo, int hi) { return min(max(v, lo), hi); }
__device__ __forceinline__ unsigned long long ullmin(unsigned long long a, unsigned long long b) {
    return (a < b) ? a : b;
}

__global__ void __launch_bounds__(256) sa_fused(
    const float* __restrict__ pos1, const float* __restrict__ pos2,
    const float* __restrict__ w1, const float* __restrict__ b1,
    const float* __restrict__ w2, const float* __restrict__ b2,
    const float* __restrict__ w3, const float* __restrict__ b3,
    float* __restrict__ out)
{
    __shared__ float4 sW1[8];       // (w1[0][o], w1[1][o], w1[2][o], b1[o])
    __shared__ float4 sW2[8][2];    // w2[i][o], i = half*4+0..3
    __shared__ float4 sW3[16][2];   // w3[i][o]
    __shared__ float  sB2v[8];
    __shared__ float  sB3v[16];

    const int t = threadIdx.x;
    if (t < 8)  sW1[t] = make_float4(w1[t], w1[8 + t], w1[16 + t], b1[t]);
    if (t < 16) { int o = t >> 1, g = (t & 1) * 4;
        sW2[o][t & 1] = make_float4(w2[g*8 + o], w2[(g+1)*8 + o], w2[(g+2)*8 + o], w2[(g+3)*8 + o]); }
    if (t < 32) { int o = t >> 1, g = (t & 1) * 4;
        sW3[o][t & 1] = make_float4(w3[g*16 + o], w3[(g+1)*16 + o], w3[(g+2)*16 + o], w3[(g+3)*16 + o]); }
    if (t < 8)  sB2v[t] = b2[t];
    if (t < 16) sB3v[t] = b3[t];
    __syncthreads();

    const int lane = t & 63;
    const int wid  = t >> 6;
    const int m    = blockIdx.x * 4 + wid;      // 0..26623
    const int b    = blockIdx.y & 1;            // batch
    const int cl   = blockIdx.y >> 1;           // cloud (0 -> pos1, 1 -> pos2)
    const float* __restrict__ base = (cl ? pos2 : pos1) + (size_t)b * (HH * WW * 3);

    const unsigned um = (unsigned)m;
    const int oh = (int)(um / OWW);
    const int ow = (int)(um - (unsigned)oh * OWW);
    const int h0 = oh * 2, w0 = ow * 4;

    const float cx = base[(h0 * WW + w0) * 3 + 0];
    const float cy = base[(h0 * WW + w0) * 3 + 1];
    const float cz = base[(h0 * WW + w0) * 3 + 2];

    const unsigned long long KINV = ~0ull;

    // ---- distances: candidate j = q*64 + lane, j in [0,240) ----
    // key = (f32 bits of d2) << 8 | j  (d2 >= 0 so bit pattern is order-preserving;
    // ties resolve to lowest j, matching stable top_k; ties only arise from
    // clip-duplicated identical points anyway, which are max-pool invariant)
    unsigned long long k[4];
    #pragma unroll
    for (int q = 0; q < 4; ++q) {
        int j  = q * 64 + lane;
        int kh = (j * 205) >> 12;       // j / 20 for j < 256
        int kw = j - kh * 20;
        int ch = iclamp(h0 - 6 + kh, 0, HH - 1);
        int cw = iclamp(w0 - 10 + kw, 0, WW - 1);
        const float* p = base + (ch * WW + cw) * 3;
        float dx = __fsub_rn(p[0], cx);
        float dy = __fsub_rn(p[1], cy);
        float dz = __fsub_rn(p[2], cz);
        // match numpy f32 ordering exactly: (dx*dx + dy*dy) + dz*dz, no FMA
        float dd = __fadd_rn(__fadd_rn(__fmul_rn(dx, dx), __fmul_rn(dy, dy)), __fmul_rn(dz, dz));
        unsigned long long key = (((unsigned long long)__float_as_uint(dd)) << 8) | (unsigned)j;
        k[q] = (j < NCAND) ? key : KINV;
    }

    // per-lane local min
    unsigned long long lkey = k[0]; int lq = 0;
    if (k[1] < lkey) { lkey = k[1]; lq = 1; }
    if (k[2] < lkey) { lkey = k[2]; lq = 2; }
    if (k[3] < lkey) { lkey = k[3]; lq = 3; }

    // ---- extract 32 smallest keys; lane i keeps the i-th winner's candidate idx ----
    int savedJ = 0;
    for (int it = 0; it < KSEL; ++it) {
        unsigned long long km = lkey;
        km = ullmin(km, __shfl_xor(km, 32));
        km = ullmin(km, __shfl_xor(km, 16));
        km = ullmin(km, __shfl_xor(km, 8));
        km = ullmin(km, __shfl_xor(km, 4));
        km = ullmin(km, __shfl_xor(km, 2));
        km = ullmin(km, __shfl_xor(km, 1));
        if (lane == it) savedJ = (int)(km & 0xFFu);
        // keys are unique -> exactly one lane owns km; it invalidates its slot
        if (lkey == km) k[lq] = KINV;
        lkey = k[0]; lq = 0;
        if (k[1] < lkey) { lkey = k[1]; lq = 1; }
        if (k[2] < lkey) { lkey = k[2]; lq = 2; }
        if (k[3] < lkey) { lkey = k[3]; lq = 3; }
    }

    // ---- MLP for lanes 0..31 (one neighbor each); lanes>=32 compute garbage, never mixed in ----
    {
        unsigned j = (unsigned)savedJ;
        int kh = (int)((j * 205u) >> 12);
        int kw = (int)j - kh * 20;
        int ch = iclamp(h0 - 6 + kh, 0, HH - 1);
        int cw = iclamp(w0 - 10 + kw, 0, WW - 1);
        const float* p = base + (ch * WW + cw) * 3;
        float rx = __fsub_rn(p[0], cx);
        float ry = __fsub_rn(p[1], cy);
        float rz = __fsub_rn(p[2], cz);

        float h1[8];
        #pragma unroll
        for (int o = 0; o < 8; ++o) {
            float4 wv = sW1[o];
            h1[o] = fmaxf(fmaf(rz, wv.z, fmaf(ry, wv.y, fmaf(rx, wv.x, wv.w))), 0.f);
        }
        float h2[8];
        #pragma unroll
        for (int o = 0; o < 8; ++o) {
            float4 a = sW2[o][0], c4 = sW2[o][1];
            float v = sB2v[o];
            v = fmaf(h1[0], a.x, v);  v = fmaf(h1[1], a.y, v);
            v = fmaf(h1[2], a.z, v);  v = fmaf(h1[3], a.w, v);
            v = fmaf(h1[4], c4.x, v); v = fmaf(h1[5], c4.y, v);
            v = fmaf(h1[6], c4.z, v); v = fmaf(h1[7], c4.w, v);
            h2[o] = fmaxf(v, 0.f);
        }
        float h3[16];
        #pragma unroll
        for (int o = 0; o < 16; ++o) {
            float4 a = sW3[o][0], c4 = sW3[o][1];
            float v = sB3v[o];
            v = fmaf(h2[0], a.x, v);  v = fmaf(h2[1], a.y, v);
            v = fmaf(h2[2], a.z, v);  v = fmaf(h2[3], a.w, v);
            v = fmaf(h2[4], c4.x, v); v = fmaf(h2[5], c4.y, v);
            v = fmaf(h2[6], c4.z, v); v = fmaf(h2[7], c4.w, v);
            h3[o] = v;  // relu deferred past max-pool (relu(max)=max(relu))
        }
        // max over 32 neighbor-lanes (xor<=16 never crosses the 32-lane halves)
        #pragma unroll
        for (int o = 0; o < 16; ++o) {
            h3[o] = fmaxf(h3[o], __shfl_xor(h3[o], 16));
            h3[o] = fmaxf(h3[o], __shfl_xor(h3[o], 8));
            h3[o] = fmaxf(h3[o], __shfl_xor(h3[o], 4));
            h3[o] = fmaxf(h3[o], __shfl_xor(h3[o], 2));
            h3[o] = fmaxf(h3[o], __shfl_xor(h3[o], 1));
        }
        if (lane == 0) {
            float4* o0 = (float4*)(out + ((size_t)(b * MM + m) * 32) + (size_t)cl * 16);
            o0[0] = make_float4(fmaxf(h3[0],  0.f), fmaxf(h3[1],  0.f), fmaxf(h3[2],  0.f), fmaxf(h3[3],  0.f));
            o0[1] = make_float4(fmaxf(h3[4],  0.f), fmaxf(h3[5],  0.f), fmaxf(h3[6],  0.f), fmaxf(h3[7],  0.f));
            o0[2] = make_float4(fmaxf(h3[8],  0.f), fmaxf(h3[9],  0.f), fmaxf(h3[10], 0.f), fmaxf(h3[11], 0.f));
            o0[3] = make_float4(fmaxf(h3[12], 0.f), fmaxf(h3[13], 0.f), fmaxf(h3[14], 0.f), fmaxf(h3[15], 0.f));
        }
    }
}

extern "C" void kernel_launch(void* const* d_in, const int* in_sizes, int n_in,
                              void* d_out, int out_size, void* d_ws, size_t ws_size,
                              hipStream_t stream) {
    const float* pos1 = (const float*)d_in[0];
    const float* pos2 = (const float*)d_in[1];
    const float* w1   = (const float*)d_in[2];
    const float* b1   = (const float*)d_in[3];
    const float* w2   = (const float*)d_in[4];
    const float* b2   = (const float*)d_in[5];
    const float* w3   = (const float*)d_in[6];
    const float* b3   = (const float*)d_in[7];
    float* out = (float*)d_out;

    dim3 grid(MM / 4, 4);   // 6656 blocks x {batch, cloud}
    sa_fused<<<grid, 256, 0, stream>>>(pos1, pos2, w1, b1, w2, b2, w3, b3, out);
}

// Round 4
// 94.867 us; speedup vs baseline: 5.7779x; 5.7779x over previous
//
#include <hip/hip_runtime.h>
#include <hip/hip_bf16.h>

#define HH 256
#define WW 832
#define OHH 128
#define OWW 208
#define NCAND 240
#define MM (OHH*OWW)

__device__ __forceinline__ int iclamp(int v, int lo, int hi) { return min(max(v, lo), hi); }
__device__ __forceinline__ int mbcnt64(unsigned long long m) {
    return __builtin_amdgcn_mbcnt_hi((unsigned)(m >> 32),
           __builtin_amdgcn_mbcnt_lo((unsigned)(m & 0xFFFFFFFFull), 0));
}

__global__ void __launch_bounds__(256) sa_fused(
    const float* __restrict__ pos1, const float* __restrict__ pos2,
    const float* __restrict__ w1, const float* __restrict__ b1,
    const float* __restrict__ w2, const float* __restrict__ b2,
    const float* __restrict__ w3, const float* __restrict__ b3,
    float* __restrict__ out)
{
    __shared__ float4 sW1[8];       // (w1[0][o], w1[1][o], w1[2][o], b1[o])
    __shared__ float4 sW2[8][2];    // w2[i][o], i = half*4+0..3
    __shared__ float4 sW3[16][2];   // w3[i][o]
    __shared__ float  sB2v[8];
    __shared__ float  sB3v[16];
    __shared__ int    selJ[128];    // 4 waves x 32 selected indices

    const int t = threadIdx.x;
    if (t < 8)  sW1[t] = make_float4(w1[t], w1[8 + t], w1[16 + t], b1[t]);
    if (t < 16) { int o = t >> 1, g = (t & 1) * 4;
        sW2[o][t & 1] = make_float4(w2[g*8 + o], w2[(g+1)*8 + o], w2[(g+2)*8 + o], w2[(g+3)*8 + o]); }
    if (t < 32) { int o = t >> 1, g = (t & 1) * 4;
        sW3[o][t & 1] = make_float4(w3[g*16 + o], w3[(g+1)*16 + o], w3[(g+2)*16 + o], w3[(g+3)*16 + o]); }
    if (t < 8)  sB2v[t] = b2[t];
    if (t < 16) sB3v[t] = b3[t];
    __syncthreads();

    const int lane = t & 63;
    const int wid  = t >> 6;
    const int m    = blockIdx.x * 4 + wid;      // 0..26623
    const int b    = blockIdx.y & 1;            // batch
    const int cl   = blockIdx.y >> 1;           // cloud (0 -> pos1, 1 -> pos2)
    const float* __restrict__ base = (cl ? pos2 : pos1) + (size_t)b * (HH * WW * 3);

    const unsigned um = (unsigned)m;
    const int oh = (int)(um / OWW);
    const int ow = (int)(um - (unsigned)oh * OWW);
    const int h0 = oh * 2, w0 = ow * 4;

    const float cx = base[(h0 * WW + w0) * 3 + 0];
    const float cy = base[(h0 * WW + w0) * 3 + 1];
    const float cz = base[(h0 * WW + w0) * 3 + 2];

    // ---- distances: candidate j = q*64 + lane, j in [0,240) ----
    // d2 >= 0 so the f32 bit pattern is order-preserving as unsigned.
    unsigned d2b[4];
    #pragma unroll
    for (int q = 0; q < 4; ++q) {
        int j  = q * 64 + lane;
        int kh = (j * 205) >> 12;       // j / 20 for j < 256
        int kw = j - kh * 20;
        int ch = iclamp(h0 - 6 + kh, 0, HH - 1);
        int cw = iclamp(w0 - 10 + kw, 0, WW - 1);
        const float* p = base + (ch * WW + cw) * 3;
        float dx = __fsub_rn(p[0], cx);
        float dy = __fsub_rn(p[1], cy);
        float dz = __fsub_rn(p[2], cz);
        // match numpy f32 ordering exactly: (dx*dx + dy*dy) + dz*dz, no FMA
        float dd = __fadd_rn(__fadd_rn(__fmul_rn(dx, dx), __fmul_rn(dy, dy)), __fmul_rn(dz, dz));
        d2b[q] = (j < NCAND) ? __float_as_uint(dd) : 0xFFFFFFFFu;
    }

    // ---- radix-select the 32nd-smallest d2 (bit construction, ballot counting) ----
    // Selection SET equals stable top_k's: {d2 < T} plus lowest-index ties at T.
    unsigned T = 0;
    unsigned long long sm0 = 0, sm1 = 0, sm2 = 0, sm3 = 0;
    bool exact = false;
    for (int bpos = 30; bpos >= 0; --bpos) {   // d2 bits <= 0x7F800000, bit31 always 0
        unsigned Q = T | (1u << bpos);
        unsigned long long t0 = __ballot(d2b[0] < Q);
        unsigned long long t1 = __ballot(d2b[1] < Q);
        unsigned long long t2 = __ballot(d2b[2] < Q);
        unsigned long long t3 = __ballot(d2b[3] < Q);
        int c = __popcll(t0) + __popcll(t1) + __popcll(t2) + __popcll(t3);
        if (c == 32) { sm0 = t0; sm1 = t1; sm2 = t2; sm3 = t3; exact = true; break; }
        if (c < 32) T = Q;   // invariant: count(d2 < T) < 32
    }
    if (!exact) {
        // T is the 32nd smallest d2 value. Take all strictly-less, then the
        // lowest-index ties at T until 32 total (== stable top_k tie rule).
        unsigned long long l0 = __ballot(d2b[0] < T);
        unsigned long long l1 = __ballot(d2b[1] < T);
        unsigned long long l2 = __ballot(d2b[2] < T);
        unsigned long long l3 = __ballot(d2b[3] < T);
        unsigned long long e0 = __ballot(d2b[0] == T);
        unsigned long long e1 = __ballot(d2b[1] == T);
        unsigned long long e2 = __ballot(d2b[2] == T);
        unsigned long long e3 = __ballot(d2b[3] == T);
        int c_lt = __popcll(l0) + __popcll(l1) + __popcll(l2) + __popcll(l3);
        int r = 32 - c_lt;
        int p1 = __popcll(e0), p2 = p1 + __popcll(e1), p3 = p2 + __popcll(e2);
        bool s0 = (d2b[0] < T) || ((d2b[0] == T) && (mbcnt64(e0) < r));
        bool s1 = (d2b[1] < T) || ((d2b[1] == T) && (p1 + mbcnt64(e1) < r));
        bool s2 = (d2b[2] < T) || ((d2b[2] == T) && (p2 + mbcnt64(e2) < r));
        bool s3 = (d2b[3] < T) || ((d2b[3] == T) && (p3 + mbcnt64(e3) < r));
        sm0 = __ballot(s0); sm1 = __ballot(s1); sm2 = __ballot(s2); sm3 = __ballot(s3);
    }

    // ---- scatter the 32 selected candidate indices to selJ[wid][0..31] ----
    {
        int b1 = __popcll(sm0);
        int b2 = b1 + __popcll(sm1);
        int b3 = b2 + __popcll(sm2);
        int lb = wid * 32;
        if ((sm0 >> lane) & 1) selJ[lb +      mbcnt64(sm0)] = lane;
        if ((sm1 >> lane) & 1) selJ[lb + b1 + mbcnt64(sm1)] = 64 + lane;
        if ((sm2 >> lane) & 1) selJ[lb + b2 + mbcnt64(sm2)] = 128 + lane;
        if ((sm3 >> lane) & 1) selJ[lb + b3 + mbcnt64(sm3)] = 192 + lane;
    }
    // same-wave LDS visibility: drain DS pipe, then read
    asm volatile("s_waitcnt lgkmcnt(0)" ::: "memory");
    __builtin_amdgcn_sched_barrier(0);

    // ---- MLP: lane l and l+32 process neighbor (l&31); halves split layer-3 channels ----
    {
        unsigned jj = (unsigned)selJ[wid * 32 + (lane & 31)];
        int kh = (int)((jj * 205u) >> 12);
        int kw = (int)jj - kh * 20;
        int ch = iclamp(h0 - 6 + kh, 0, HH - 1);
        int cw = iclamp(w0 - 10 + kw, 0, WW - 1);
        const float* p = base + (ch * WW + cw) * 3;
        float rx = __fsub_rn(p[0], cx);
        float ry = __fsub_rn(p[1], cy);
        float rz = __fsub_rn(p[2], cz);

        float h1[8];
        #pragma unroll
        for (int o = 0; o < 8; ++o) {
            float4 wv = sW1[o];
            h1[o] = fmaxf(fmaf(rz, wv.z, fmaf(ry, wv.y, fmaf(rx, wv.x, wv.w))), 0.f);
        }
        float h2[8];
        #pragma unroll
        for (int o = 0; o < 8; ++o) {
            float4 a = sW2[o][0], c4 = sW2[o][1];
            float v = sB2v[o];
            v = fmaf(h1[0], a.x, v);  v = fmaf(h1[1], a.y, v);
            v = fmaf(h1[2], a.z, v);  v = fmaf(h1[3], a.w, v);
            v = fmaf(h1[4], c4.x, v); v = fmaf(h1[5], c4.y, v);
            v = fmaf(h1[6], c4.z, v); v = fmaf(h1[7], c4.w, v);
            h2[o] = fmaxf(v, 0.f);
        }
        const int ob = (lane >> 5) << 3;    // lanes 0-31: ch 0-7; lanes 32-63: ch 8-15
        float h3[8];
        #pragma unroll
        for (int o = 0; o < 8; ++o) {
            float4 a = sW3[ob + o][0], c4 = sW3[ob + o][1];
            float v = sB3v[ob + o];
            v = fmaf(h2[0], a.x, v);  v = fmaf(h2[1], a.y, v);
            v = fmaf(h2[2], a.z, v);  v = fmaf(h2[3], a.w, v);
            v = fmaf(h2[4], c4.x, v); v = fmaf(h2[5], c4.y, v);
            v = fmaf(h2[6], c4.z, v); v = fmaf(h2[7], c4.w, v);
            h3[o] = v;  // relu deferred past max-pool (relu(max)=max(relu))
        }
        // max over the 32 neighbor-lanes within each half (xor<=16 keeps halves separate)
        #pragma unroll
        for (int o = 0; o < 8; ++o) {
            h3[o] = fmaxf(h3[o], __shfl_xor(h3[o], 16));
            h3[o] = fmaxf(h3[o], __shfl_xor(h3[o], 8));
            h3[o] = fmaxf(h3[o], __shfl_xor(h3[o], 4));
            h3[o] = fmaxf(h3[o], __shfl_xor(h3[o], 2));
            h3[o] = fmaxf(h3[o], __shfl_xor(h3[o], 1));
        }
        if ((lane & 31) == 0) {
            float4* dst = (float4*)(out + ((size_t)(b * MM + m) * 32) + (size_t)cl * 16 + ob);
            dst[0] = make_float4(fmaxf(h3[0], 0.f), fmaxf(h3[1], 0.f), fmaxf(h3[2], 0.f), fmaxf(h3[3], 0.f));
            dst[1] = make_float4(fmaxf(h3[4], 0.f), fmaxf(h3[5], 0.f), fmaxf(h3[6], 0.f), fmaxf(h3[7], 0.f));
        }
    }
}

extern "C" void kernel_launch(void* const* d_in, const int* in_sizes, int n_in,
                              void* d_out, int out_size, void* d_ws, size_t ws_size,
                              hipStream_t stream) {
    const float* pos1 = (const float*)d_in[0];
    const float* pos2 = (const float*)d_in[1];
    const float* w1   = (const float*)d_in[2];
    const float* b1   = (const float*)d_in[3];
    const float* w2   = (const float*)d_in[4];
    const float* b2   = (const float*)d_in[5];
    const float* w3   = (const float*)d_in[6];
    const float* b3   = (const float*)d_in[7];
    float* out = (float*)d_out;

    dim3 grid(MM / 4, 4);   // 6656 blocks x {batch, cloud}
    sa_fused<<<grid, 256, 0, stream>>>(pos1, pos2, w1, b1, w2, b2, w3, b3, out);
}